// Round 1
// baseline (522.022 us; speedup 1.0000x reference)
//
#include <hip/hip_runtime.h>
#include <stdint.h>

#define NPIX 9216   // 96*96
#define CIN 64
#define DD 24
#define DP 32       // padded head dim (24 -> 32, zeros)

typedef __attribute__((ext_vector_type(8))) short short8;   // 8 bf16 (guide-verified frag type)
typedef __attribute__((ext_vector_type(4))) float f32x4;
typedef __attribute__((ext_vector_type(4))) unsigned int u32x4;

__device__ __forceinline__ unsigned short f2bf(float f) {
    // round-to-nearest-even fp32 -> bf16
    unsigned int u = __builtin_bit_cast(unsigned int, f);
    u += 0x7fffu + ((u >> 16) & 1u);
    return (unsigned short)(u >> 16);
}

// ---------------- Kernel 1: QKV projection ----------------
// x: [B, 64, N] f32.
// qr, kr: [B, N, 32] bf16 rows (q pre-scaled by log2(e)/sqrt(24)); vdn: [B, 32, N] bf16.
__global__ __launch_bounds__(128) void qkv_proj_kernel(
    const float* __restrict__ x,
    const float* __restrict__ wq, const float* __restrict__ bq,
    const float* __restrict__ wk, const float* __restrict__ bk,
    const float* __restrict__ wv, const float* __restrict__ bv,
    unsigned short* __restrict__ qr, unsigned short* __restrict__ kr,
    unsigned short* __restrict__ vdn)
{
    const int tid = blockIdx.x * 128 + threadIdx.x;
    const int b = tid / NPIX;            // block fully inside one batch (9216 % 128 == 0)
    const int n = tid - b * NPIX;
    const float* xb = x + (size_t)b * CIN * NPIX + n;
    float xv[CIN];
#pragma unroll
    for (int c2 = 0; c2 < CIN; ++c2) xv[c2] = xb[(size_t)c2 * NPIX];

    // fold softmax scale AND log2(e) into q so exp becomes a bare v_exp_f32
    const float qscale = (float)(0.20412414523193154 * 1.4426950408889634);

    alignas(16) unsigned short qrow[DP];
    alignas(16) unsigned short krow[DP];
#pragma unroll
    for (int d2 = DD; d2 < DP; ++d2) { qrow[d2] = 0; krow[d2] = 0; }

    const size_t vbase = (size_t)b * DP * NPIX + n;
    for (int d2 = 0; d2 < DD; ++d2) {
        float aq = bq[d2], ak = bk[d2], av = bv[d2];
        const float* wqd = wq + d2 * CIN;
        const float* wkd = wk + d2 * CIN;
        const float* wvd = wv + d2 * CIN;
#pragma unroll
        for (int c2 = 0; c2 < CIN; ++c2) {   // weights: wave-uniform -> scalar loads
            aq = fmaf(wqd[c2], xv[c2], aq);
            ak = fmaf(wkd[c2], xv[c2], ak);
            av = fmaf(wvd[c2], xv[c2], av);
        }
        qrow[d2] = f2bf(aq * qscale);
        krow[d2] = f2bf(ak);
        vdn[vbase + (size_t)d2 * NPIX] = f2bf(av);
    }
#pragma unroll
    for (int d2 = DD; d2 < DP; ++d2) vdn[vbase + (size_t)d2 * NPIX] = 0;

    const size_t rbase = (size_t)(b * NPIX + n) * DP;
    const u32x4* q4 = (const u32x4*)qrow;
    const u32x4* k4 = (const u32x4*)krow;
    u32x4* qo = (u32x4*)(qr + rbase);
    u32x4* ko = (u32x4*)(kr + rbase);
#pragma unroll
    for (int i = 0; i < 4; ++i) { qo[i] = q4[i]; ko[i] = k4[i]; }
}

// ---------------- Kernel 2: flash attention + output projection ----------------
// grid (144, 4): blockIdx.x = 64-row Q tile, blockIdx.y = batch. 256 threads = 4 waves,
// each wave owns 16 Q rows. K/V tiles of 128 j staged in LDS (padded strides: 80B / 272B
// rows -> <=2-way bank aliasing, free per m136).
__global__ __launch_bounds__(256) void attn_kernel(
    const unsigned short* __restrict__ qr,
    const unsigned short* __restrict__ kr,
    const unsigned short* __restrict__ vdn,
    const float* __restrict__ wo, const float* __restrict__ bo,
    float* __restrict__ out)
{
    __shared__ unsigned short k_lds[128][40];   // [j][k], stride 80B (5*16B, coprime 8)
    __shared__ unsigned short v_lds[32][136];   // [d][j], stride 272B (17*16B)
    __shared__ unsigned short p_lds[4][16][40]; // per-wave P relayout buffer
    __shared__ float o_scr[4][16][34];          // per-wave O transpose for out-proj
    __shared__ float wo_lds[64 * DD];
    __shared__ float bo_lds[64];

    const int b = blockIdx.y;
    const int tile = blockIdx.x;
    const int t = threadIdx.x;
    const int w = t >> 6;
    const int lane = t & 63;
    const int g = lane >> 4;    // k-group of the fragment
    const int c = lane & 15;    // row (A) / col (B) index within 16

    for (int i = t; i < 64 * DD; i += 256) wo_lds[i] = wo[i];
    if (t < 64) bo_lds[t] = bo[t];

    const int qbase = tile * 64 + w * 16;
    // A-fragment of Q: lane holds Q[qbase+c][8g..8g+7]
    const short8 qf = *(const short8*)(qr + ((size_t)(b * NPIX + qbase + c)) * DP + g * 8);

    const unsigned short* kb = kr + (size_t)b * NPIX * DP;
    const unsigned short* vb = vdn + (size_t)b * DP * NPIX;

    f32x4 acc0 = {0.f, 0.f, 0.f, 0.f};  // O[4g+r][c]      (d = 0..15)
    f32x4 acc1 = {0.f, 0.f, 0.f, 0.f};  // O[4g+r][16+c]   (d = 16..31)
    float m[4] = {-INFINITY, -INFINITY, -INFINITY, -INFINITY};  // log2-domain running max
    float l[4] = {0.f, 0.f, 0.f, 0.f};

    const f32x4 zf = {0.f, 0.f, 0.f, 0.f};

    for (int jt = 0; jt < NPIX; jt += 128) {
        __syncthreads();   // protect LDS from previous iteration's readers
        {   // stage K tile: thread t -> row t>>1, 32B half t&1
            const int row = t >> 1, half = t & 1;
            const u32x4* src = (const u32x4*)(kb + (size_t)(jt + row) * DP + half * 16);
            u32x4 a0 = src[0], a1 = src[1];
            *(u32x4*)&k_lds[row][half * 16] = a0;
            *(u32x4*)&k_lds[row][half * 16 + 8] = a1;
        }
        {   // stage V tile: thread t -> d-row t>>3, 32B part t&7
            const int d = t >> 3, part = t & 7;
            const u32x4* src = (const u32x4*)(vb + (size_t)d * NPIX + jt + part * 16);
            u32x4 a0 = src[0], a1 = src[1];
            *(u32x4*)&v_lds[d][part * 16] = a0;
            *(u32x4*)&v_lds[d][part * 16 + 8] = a1;
        }
        __syncthreads();

#pragma unroll
        for (int sub = 0; sub < 4; ++sub) {
            const int j0 = sub * 32;
            // B-fragments of K^T: lane holds K[jt+j0(+16)+c][8g..8g+7]
            const short8 kf0 = *(const short8*)&k_lds[j0 + c][g * 8];
            const short8 kf1 = *(const short8*)&k_lds[j0 + 16 + c][g * 8];
            f32x4 s0 = __builtin_amdgcn_mfma_f32_16x16x32_bf16(qf, kf0, zf, 0, 0, 0);
            f32x4 s1 = __builtin_amdgcn_mfma_f32_16x16x32_bf16(qf, kf1, zf, 0, 0, 0);
            // s{0,1}[r] = S2[4g+r][c(+16)] in log2 domain (scale folded into q)

            float pm[4];
#pragma unroll
            for (int r = 0; r < 4; ++r) pm[r] = fmaxf(s0[r], s1[r]);
#pragma unroll
            for (int off = 1; off < 16; off <<= 1) {
#pragma unroll
                for (int r = 0; r < 4; ++r) pm[r] = fmaxf(pm[r], __shfl_xor(pm[r], off));
            }
            float p0[4], p1[4], rs[4], al[4];
#pragma unroll
            for (int r = 0; r < 4; ++r) {
                const float mn = fmaxf(m[r], pm[r]);
                al[r] = __builtin_amdgcn_exp2f(m[r] - mn);   // exp2(-inf)=0 on first tile
                p0[r] = __builtin_amdgcn_exp2f(s0[r] - mn);
                p1[r] = __builtin_amdgcn_exp2f(s1[r] - mn);
                m[r] = mn;
                rs[r] = p0[r] + p1[r];
            }
#pragma unroll
            for (int off = 1; off < 16; off <<= 1) {
#pragma unroll
                for (int r = 0; r < 4; ++r) rs[r] += __shfl_xor(rs[r], off);
            }
#pragma unroll
            for (int r = 0; r < 4; ++r) {
                l[r] = l[r] * al[r] + rs[r];
                acc0[r] *= al[r];
                acc1[r] *= al[r];
            }
            // P: C-layout -> A-fragment via per-wave LDS (intra-wave, no barrier needed)
#pragma unroll
            for (int r = 0; r < 4; ++r) {
                p_lds[w][4 * g + r][c] = f2bf(p0[r]);
                p_lds[w][4 * g + r][16 + c] = f2bf(p1[r]);
            }
            const short8 pf = *(const short8*)&p_lds[w][c][g * 8];
            const short8 vf0 = *(const short8*)&v_lds[c][j0 + g * 8];
            const short8 vf1 = *(const short8*)&v_lds[16 + c][j0 + g * 8];
            acc0 = __builtin_amdgcn_mfma_f32_16x16x32_bf16(pf, vf0, acc0, 0, 0, 0);
            acc1 = __builtin_amdgcn_mfma_f32_16x16x32_bf16(pf, vf1, acc1, 0, 0, 0);
        }
    }
    __syncthreads();

    // normalize + transpose O through LDS, then 1x1 out-projection
#pragma unroll
    for (int r = 0; r < 4; ++r) {
        const float inv = 1.0f / l[r];
        o_scr[w][4 * g + r][c] = acc0[r] * inv;
        o_scr[w][4 * g + r][16 + c] = acc1[r] * inv;
    }
    __syncthreads();

    float orow[DD];
#pragma unroll
    for (int d = 0; d < DD; ++d) orow[d] = o_scr[w][c][d];   // broadcast reads

    const int n_glob = qbase + c;
#pragma unroll
    for (int tt = 0; tt < 16; ++tt) {
        const int o = g + 4 * tt;
        float a = bo_lds[o];
#pragma unroll
        for (int d = 0; d < DD; ++d) a = fmaf(wo_lds[o * DD + d], orow[d], a);
        out[((size_t)(b * 64 + o)) * NPIX + n_glob] = a;
    }
}

extern "C" void kernel_launch(void* const* d_in, const int* in_sizes, int n_in,
                              void* d_out, int out_size, void* d_ws, size_t ws_size,
                              hipStream_t stream) {
    const float* x  = (const float*)d_in[0];
    const float* wq = (const float*)d_in[1];
    const float* bq = (const float*)d_in[2];
    const float* wk = (const float*)d_in[3];
    const float* bk = (const float*)d_in[4];
    const float* wv = (const float*)d_in[5];
    const float* bv = (const float*)d_in[6];
    const float* wo = (const float*)d_in[7];
    const float* bo = (const float*)d_in[8];
    float* out = (float*)d_out;

    unsigned short* qr  = (unsigned short*)d_ws;              // 4*9216*32 bf16 = 2.36 MB
    unsigned short* kr  = qr + (size_t)4 * NPIX * DP;
    unsigned short* vdn = kr + (size_t)4 * NPIX * DP;         // total ws use: 7.08 MB

    hipLaunchKernelGGL(qkv_proj_kernel, dim3(4 * NPIX / 128), dim3(128), 0, stream,
                       x, wq, bq, wk, bk, wv, bv, qr, kr, vdn);
    hipLaunchKernelGGL(attn_kernel, dim3(NPIX / 64, 4), dim3(256), 0, stream,
                       qr, kr, vdn, wo, bo, out);
}

// Round 3
// 202.643 us; speedup vs baseline: 2.5761x; 2.5761x over previous
//
#include <hip/hip_runtime.h>
#include <stdint.h>

#define NPIX 9216   // 96*96
#define CIN 64
#define DD 24
#define DP 32       // padded head dim (24 -> 32, zeros)

typedef __attribute__((ext_vector_type(8))) short short8;   // 8 bf16
typedef __attribute__((ext_vector_type(4))) float f32x4;
typedef __attribute__((ext_vector_type(4))) unsigned int u32x4;

__device__ __forceinline__ unsigned short f2bf(float f) {
    unsigned int u = __builtin_bit_cast(unsigned int, f);
    u += 0x7fffu + ((u >> 16) & 1u);
    return (unsigned short)(u >> 16);
}
__device__ __forceinline__ unsigned int pkbf(float lo, float hi) {
    return (unsigned int)f2bf(lo) | ((unsigned int)f2bf(hi) << 16);
}

// ---------------- Kernel 1: QKV projection ----------------
// x: [B, 64, N] f32 -> qr, kr: [B, N, 32] bf16 (q pre-scaled by log2e/sqrt(24));
// vdn: [B, 32, N] bf16 (d-major, rows 24..31 zero).
__global__ __launch_bounds__(128) void qkv_proj_kernel(
    const float* __restrict__ x,
    const float* __restrict__ wq, const float* __restrict__ bq,
    const float* __restrict__ wk, const float* __restrict__ bk,
    const float* __restrict__ wv, const float* __restrict__ bv,
    unsigned short* __restrict__ qr, unsigned short* __restrict__ kr,
    unsigned short* __restrict__ vdn)
{
    const int tid = blockIdx.x * 128 + threadIdx.x;
    const int b = tid / NPIX;
    const int n = tid - b * NPIX;
    const float* xb = x + (size_t)b * CIN * NPIX + n;
    float xv[CIN];
#pragma unroll
    for (int c2 = 0; c2 < CIN; ++c2) xv[c2] = xb[(size_t)c2 * NPIX];

    const float qscale = (float)(0.20412414523193154 * 1.4426950408889634);

    alignas(16) unsigned short qrow[DP];
    alignas(16) unsigned short krow[DP];
#pragma unroll
    for (int d2 = DD; d2 < DP; ++d2) { qrow[d2] = 0; krow[d2] = 0; }

    {   // Q and K: 48 independent FMA chains (ILP), weights are wave-uniform s_loads
        float aq[DD], ak[DD];
#pragma unroll
        for (int d = 0; d < DD; ++d) { aq[d] = bq[d]; ak[d] = bk[d]; }
#pragma unroll 4
        for (int c2 = 0; c2 < CIN; ++c2) {
            const float xc = xv[c2];
#pragma unroll
            for (int d = 0; d < DD; ++d) {
                aq[d] = fmaf(wq[d * CIN + c2], xc, aq[d]);
                ak[d] = fmaf(wk[d * CIN + c2], xc, ak[d]);
            }
        }
#pragma unroll
        for (int d = 0; d < DD; ++d) {
            qrow[d] = f2bf(aq[d] * qscale);
            krow[d] = f2bf(ak[d]);
        }
    }
    {   // V: 24 chains
        float av[DD];
#pragma unroll
        for (int d = 0; d < DD; ++d) av[d] = bv[d];
#pragma unroll 4
        for (int c2 = 0; c2 < CIN; ++c2) {
            const float xc = xv[c2];
#pragma unroll
            for (int d = 0; d < DD; ++d) av[d] = fmaf(wv[d * CIN + c2], xc, av[d]);
        }
        const size_t vbase = (size_t)b * DP * NPIX + n;
#pragma unroll
        for (int d = 0; d < DD; ++d) vdn[vbase + (size_t)d * NPIX] = f2bf(av[d]);
#pragma unroll
        for (int d = DD; d < DP; ++d) vdn[vbase + (size_t)d * NPIX] = 0;
    }

    const size_t rbase = (size_t)(b * NPIX + n) * DP;
    const u32x4* q4 = (const u32x4*)qrow;
    const u32x4* k4 = (const u32x4*)krow;
    u32x4* qo = (u32x4*)(qr + rbase);
    u32x4* ko = (u32x4*)(kr + rbase);
#pragma unroll
    for (int i = 0; i < 4; ++i) { qo[i] = q4[i]; ko[i] = k4[i]; }
}

// ---------------- Kernel 2: flash attention (swapped QK^T) + out projection ----------------
// grid (144, 4), 512 threads = 8 waves. Waves 0-3: j in [0,4608), waves 4-7: [4608,9216);
// wave w owns q-subtile (w&3)*16 of the 64-row Q tile. Partials merged in LDS at the end.
// K rows are staged into LDS bit-permuted so that after S^T = mfma(K,Q), each lane's
// exp'd P values are exactly its PV B-fragment (no cross-lane P relayout at all).
__global__ __launch_bounds__(512) void attn_kernel(
    const unsigned short* __restrict__ qr,
    const unsigned short* __restrict__ kr,
    const unsigned short* __restrict__ vdn,
    const float* __restrict__ wo, const float* __restrict__ bo,
    float* __restrict__ out)
{
    __shared__ __align__(16) unsigned char pool[37888]; // K: [2][128][40]u16 @0 (20480), V: [2][32][136]u16 @20480 (17408)
    __shared__ float wo_lds[64 * DD];
    __shared__ float bo_lds[64];

    unsigned short* kpool = (unsigned short*)pool;
    unsigned short* vpool = (unsigned short*)(pool + 20480);

    const int b = blockIdx.y;
    const int tile = blockIdx.x;
    const int t = threadIdx.x;
    const int w = t >> 6;
    const int lane = t & 63;
    const int g = lane >> 4;
    const int c = lane & 15;
    const int jh = w >> 2;   // j-half
    const int sq = w & 3;    // q-subtile

    for (int i = t; i < 64 * DD; i += 512) wo_lds[i] = wo[i];
    if (t < 64) bo_lds[t] = bo[t];

    const int qrow_g = tile * 64 + sq * 16 + c;
    const short8 qf = *(const short8*)(qr + ((size_t)(b * NPIX + qrow_g)) * DP + g * 8);

    const unsigned short* kb = kr + (size_t)b * NPIX * DP;
    const unsigned short* vb = vdn + (size_t)b * DP * NPIX;

    // --- staging decomposition (512 threads) ---
    // K: thread -> (row pair): row = t>>1 in [0,256), 32B half = t&1. Bit-permuted dest row.
    const int krow = t >> 1, khw = t & 1;
    const int kh = krow >> 7, kjn = krow & 127;
    const int klow = kjn & 63;
    const int kR = (kjn & 64) + ((klow >> 5) & 1) * 32 + ((klow >> 2) & 1) * 16
                 + ((klow >> 4) & 1) * 8 + ((klow >> 3) & 1) * 4 + (klow & 3);
    unsigned short* kdst = kpool + kh * 5120 + kR * 40 + khw * 16;
    const unsigned short* ksrc0 = kb + ((size_t)(kh * 4608 + kjn)) * DP + khw * 16;
    // V: natural order. thread -> (half, d, 32B part)
    const int vh = t >> 8, vd = (t >> 3) & 31, vpt = t & 7;
    unsigned short* vdst = vpool + vh * 4352 + vd * 136 + vpt * 16;
    const unsigned short* vsrc0 = vb + (size_t)vd * NPIX + vh * 4608 + vpt * 16;

    const unsigned short* kT = kpool + jh * 5120;   // this wave's K buffer [128][40]
    const unsigned short* vT = vpool + jh * 4352;   // this wave's V buffer [32][136]

    f32x4 acc0 = {0.f, 0.f, 0.f, 0.f};   // O^T[d=4g+r][q=c]   (unnormalized)
    f32x4 acc1 = {0.f, 0.f, 0.f, 0.f};   // O^T[16+4g+r][q=c]
    float m = -INFINITY, l = 0.f;        // per-q running max (log2 domain) / denom
    const f32x4 zf = {0.f, 0.f, 0.f, 0.f};

    for (int it = 0; it < 36; ++it) {
        const int jt = it * 128;
        __syncthreads();
        {   // stage both halves' K/V tiles
            const u32x4* sk = (const u32x4*)(ksrc0 + (size_t)jt * DP);
            u32x4 a0 = sk[0], a1 = sk[1];
            *(u32x4*)kdst = a0; *(u32x4*)(kdst + 8) = a1;
            const u32x4* sv = (const u32x4*)(vsrc0 + jt);
            u32x4 b0 = sv[0], b1 = sv[1];
            *(u32x4*)vdst = b0; *(u32x4*)(vdst + 8) = b1;
        }
        __syncthreads();

#pragma unroll
        for (int u = 0; u < 2; ++u) {   // two 64-j groups per 128-tile
            const int jb = u * 64;
            const short8 kf0 = *(const short8*)(kT + (jb +  0 + c) * 40 + g * 8);
            const short8 kf1 = *(const short8*)(kT + (jb + 16 + c) * 40 + g * 8);
            const short8 kf2 = *(const short8*)(kT + (jb + 32 + c) * 40 + g * 8);
            const short8 kf3 = *(const short8*)(kT + (jb + 48 + c) * 40 + g * 8);
            // S^T = K . Q^T : lane (g,c) reg r holds S for q=c, k-label 8g+4(t&1)+r
            f32x4 s0 = __builtin_amdgcn_mfma_f32_16x16x32_bf16(kf0, qf, zf, 0, 0, 0);
            f32x4 s1 = __builtin_amdgcn_mfma_f32_16x16x32_bf16(kf1, qf, zf, 0, 0, 0);
            f32x4 s2 = __builtin_amdgcn_mfma_f32_16x16x32_bf16(kf2, qf, zf, 0, 0, 0);
            f32x4 s3 = __builtin_amdgcn_mfma_f32_16x16x32_bf16(kf3, qf, zf, 0, 0, 0);

            float a0 = fmaxf(fmaxf(s0[0], s0[1]), fmaxf(s0[2], s0[3]));
            float a1 = fmaxf(fmaxf(s1[0], s1[1]), fmaxf(s1[2], s1[3]));
            float a2 = fmaxf(fmaxf(s2[0], s2[1]), fmaxf(s2[2], s2[3]));
            float a3 = fmaxf(fmaxf(s3[0], s3[1]), fmaxf(s3[2], s3[3]));
            float pmax = fmaxf(fmaxf(a0, a1), fmaxf(a2, a3));
            pmax = fmaxf(pmax, __shfl_xor(pmax, 16));
            pmax = fmaxf(pmax, __shfl_xor(pmax, 32));
            const float mn = fmaxf(m, pmax);
            const float al = __builtin_amdgcn_exp2f(m - mn);   // 0 on first tile
            m = mn;

            float p0[4], p1[4], p2[4], p3[4];
#pragma unroll
            for (int r = 0; r < 4; ++r) {
                p0[r] = __builtin_amdgcn_exp2f(s0[r] - mn);
                p1[r] = __builtin_amdgcn_exp2f(s1[r] - mn);
                p2[r] = __builtin_amdgcn_exp2f(s2[r] - mn);
                p3[r] = __builtin_amdgcn_exp2f(s3[r] - mn);
            }
            float rs = ((p0[0] + p0[1]) + (p0[2] + p0[3])) + ((p1[0] + p1[1]) + (p1[2] + p1[3]))
                     + ((p2[0] + p2[1]) + (p2[2] + p2[3])) + ((p3[0] + p3[1]) + (p3[2] + p3[3]));
            rs += __shfl_xor(rs, 16);
            rs += __shfl_xor(rs, 32);
            l = l * al + rs;
#pragma unroll
            for (int r = 0; r < 4; ++r) { acc0[r] *= al; acc1[r] *= al; }

            // lane-local B-fragments of P^T (thanks to the K-row permutation)
            union { short8 s8; unsigned int u32[4]; } b2a, b2b;
            b2a.u32[0] = pkbf(p0[0], p0[1]); b2a.u32[1] = pkbf(p0[2], p0[3]);
            b2a.u32[2] = pkbf(p1[0], p1[1]); b2a.u32[3] = pkbf(p1[2], p1[3]);
            b2b.u32[0] = pkbf(p2[0], p2[1]); b2b.u32[1] = pkbf(p2[2], p2[3]);
            b2b.u32[2] = pkbf(p3[0], p3[1]); b2b.u32[3] = pkbf(p3[2], p3[3]);

            const short8 vl0 = *(const short8*)(vT + (c)      * 136 + jb +      g * 8);
            const short8 vh0 = *(const short8*)(vT + (16 + c) * 136 + jb +      g * 8);
            const short8 vl1 = *(const short8*)(vT + (c)      * 136 + jb + 32 + g * 8);
            const short8 vh1 = *(const short8*)(vT + (16 + c) * 136 + jb + 32 + g * 8);
            // O^T += V^T . P^T
            acc0 = __builtin_amdgcn_mfma_f32_16x16x32_bf16(vl0, b2a.s8, acc0, 0, 0, 0);
            acc1 = __builtin_amdgcn_mfma_f32_16x16x32_bf16(vh0, b2a.s8, acc1, 0, 0, 0);
            acc0 = __builtin_amdgcn_mfma_f32_16x16x32_bf16(vl1, b2b.s8, acc0, 0, 0, 0);
            acc1 = __builtin_amdgcn_mfma_f32_16x16x32_bf16(vh1, b2b.s8, acc1, 0, 0, 0);
        }
    }
    __syncthreads();   // staging buffers dead; reuse pool as merge scratch

    float* om  = (float*)pool;            // [8][16][36]  (18432 B)
    float* mlb = (float*)(pool + 20480);  // [8][16][2]
    *(f32x4*)(om + (w * 16 + c) * 36 + 4 * g) = acc0;
    *(f32x4*)(om + (w * 16 + c) * 36 + 16 + 4 * g) = acc1;
    if (g == 0) { mlb[(w * 16 + c) * 2] = m; mlb[(w * 16 + c) * 2 + 1] = l; }
    __syncthreads();

    // merge the two j-half partials for q-subtile sq, then 1x1 out-projection.
    // waves sq and sq+4 compute the same orw; they write disjoint output-channel halves.
    const float mA = mlb[(sq * 16 + c) * 2],       lA = mlb[(sq * 16 + c) * 2 + 1];
    const float mB = mlb[((sq + 4) * 16 + c) * 2], lB = mlb[((sq + 4) * 16 + c) * 2 + 1];
    const float M  = fmaxf(mA, mB);
    const float wA = __builtin_amdgcn_exp2f(mA - M);
    const float wB = __builtin_amdgcn_exp2f(mB - M);
    const float inv = 1.0f / (lA * wA + lB * wB);
    float orw[DD];
#pragma unroll
    for (int d = 0; d < DD; ++d)
        orw[d] = (om[(sq * 16 + c) * 36 + d] * wA + om[((sq + 4) * 16 + c) * 36 + d] * wB) * inv;

#pragma unroll
    for (int tt = 0; tt < 8; ++tt) {
        const int o = g + 4 * (jh * 8 + tt);
        float a = bo_lds[o];
#pragma unroll
        for (int d = 0; d < DD; ++d) a = fmaf(wo_lds[o * DD + d], orw[d], a);
        out[((size_t)(b * 64 + o)) * NPIX + qrow_g] = a;
    }
}

extern "C" void kernel_launch(void* const* d_in, const int* in_sizes, int n_in,
                              void* d_out, int out_size, void* d_ws, size_t ws_size,
                              hipStream_t stream) {
    const float* x  = (const float*)d_in[0];
    const float* wq = (const float*)d_in[1];
    const float* bq = (const float*)d_in[2];
    const float* wk = (const float*)d_in[3];
    const float* bk = (const float*)d_in[4];
    const float* wv = (const float*)d_in[5];
    const float* bv = (const float*)d_in[6];
    const float* wo = (const float*)d_in[7];
    const float* bo = (const float*)d_in[8];
    float* out = (float*)d_out;

    unsigned short* qr  = (unsigned short*)d_ws;
    unsigned short* kr  = qr + (size_t)4 * NPIX * DP;
    unsigned short* vdn = kr + (size_t)4 * NPIX * DP;   // total ws use: 7.08 MB

    hipLaunchKernelGGL(qkv_proj_kernel, dim3(4 * NPIX / 128), dim3(128), 0, stream,
                       x, wq, bq, wk, bk, wv, bv, qr, kr, vdn);
    hipLaunchKernelGGL(attn_kernel, dim3(NPIX / 64, 4), dim3(512), 0, stream,
                       qr, kr, vdn, wo, bo, out);
}

// Round 5
// 130.772 us; speedup vs baseline: 3.9918x; 1.5496x over previous
//
#include <hip/hip_runtime.h>
#include <stdint.h>

#define NPIX 9216   // 96*96
#define CIN 64
#define DD 24
#define DP 32       // padded head dim (24 -> 32, zeros)

typedef __attribute__((ext_vector_type(8))) short short8;   // 8 bf16
typedef __attribute__((ext_vector_type(4))) float f32x4;
typedef __attribute__((ext_vector_type(4))) unsigned int u32x4;

__device__ __forceinline__ unsigned short f2bf(float f) {
    unsigned int u = __builtin_bit_cast(unsigned int, f);
    u += 0x7fffu + ((u >> 16) & 1u);
    return (unsigned short)(u >> 16);
}
// packed f32x2 -> bf16x2 in one VALU op (T12 recipe; dst.lo = first operand)
__device__ __forceinline__ unsigned int pkbf(float lo, float hi) {
    unsigned int r;
    asm("v_cvt_pk_bf16_f32 %0, %1, %2" : "=v"(r) : "v"(lo), "v"(hi));
    return r;
}

// ---------------- Kernel 1: QKV projection (one proj per thread) ----------------
// grid (144, 3): blockIdx.y = projection (0=Q,1=K,2=V).
// qr, kr: [B, N, 32] bf16 (q pre-scaled by log2e/sqrt(24)); vdn: [B, 24, N] bf16.
__global__ __launch_bounds__(256) void qkv_proj_kernel(
    const float* __restrict__ x,
    const float* __restrict__ wq, const float* __restrict__ bq,
    const float* __restrict__ wk, const float* __restrict__ bk,
    const float* __restrict__ wv, const float* __restrict__ bv,
    unsigned short* __restrict__ qr, unsigned short* __restrict__ kr,
    unsigned short* __restrict__ vdn)
{
    const int p = blockIdx.y;
    const int tid = blockIdx.x * 256 + threadIdx.x;
    const int b = tid / NPIX;
    const int n = tid - b * NPIX;
    const float* xb = x + (size_t)b * CIN * NPIX + n;
    float xv[CIN];
#pragma unroll
    for (int c = 0; c < CIN; ++c) xv[c] = xb[(size_t)c * NPIX];

    const float* wm = (p == 0) ? wq : (p == 1) ? wk : wv;
    const float* bm = (p == 0) ? bq : (p == 1) ? bk : bv;

    float acc[DD];
#pragma unroll
    for (int d = 0; d < DD; ++d) acc[d] = bm[d];
#pragma unroll 4
    for (int c = 0; c < CIN; ++c) {
        const float xc = xv[c];
#pragma unroll
        for (int d = 0; d < DD; ++d) acc[d] = fmaf(wm[d * CIN + c], xc, acc[d]);
    }

    if (p == 2) {           // V: d-major rows 0..23 (rows 24..31 built in attn LDS)
        const size_t vbase = (size_t)b * DD * NPIX + n;
#pragma unroll
        for (int d = 0; d < DD; ++d) vdn[vbase + (size_t)d * NPIX] = f2bf(acc[d]);
    } else {
        alignas(16) unsigned short row[DP];
        const float sc = (p == 0) ? (float)(0.20412414523193154 * 1.4426950408889634) : 1.0f;
#pragma unroll
        for (int d = 0; d < DD; ++d) row[d] = f2bf(acc[d] * sc);
#pragma unroll
        for (int d = DD; d < DP; ++d) row[d] = 0;
        unsigned short* dst = ((p == 0) ? qr : kr) + (size_t)(b * NPIX + n) * DP;
        const u32x4* r4 = (const u32x4*)row;
#pragma unroll
        for (int i = 0; i < 4; ++i) ((u32x4*)dst)[i] = r4[i];
    }
}

// ---------------- Kernel 2: flash attention (16x16 MFMA, r3-verified layout) ----------------
// grid (144, 4), 512 threads = 8 waves. Waves 0-3: j in [0,4608), waves 4-7: [4608,9216);
// wave w owns q-subtile (w&3)*16. K rows staged bit-permuted (r3-verified) so exp'd P
// packs pairwise into PV B-fragments with zero cross-lane movement. V LDS row 24 = 1.0
// -> PV MFMA's row 24 accumulates the softmax denominator for free (auto-rescaled).
__global__ __launch_bounds__(512) void attn_kernel(
    const unsigned short* __restrict__ qr,
    const unsigned short* __restrict__ kr,
    const unsigned short* __restrict__ vdn,
    const float* __restrict__ wo, const float* __restrict__ bo,
    float* __restrict__ out)
{
    __shared__ __align__(16) unsigned char pool[37888]; // K: [2][128][40]u16 @0, V: [2][32][136]u16 @20480
    __shared__ float wo_lds[64 * DD];
    __shared__ float bo_lds[64];

    unsigned short* kpool = (unsigned short*)pool;
    unsigned short* vpool = (unsigned short*)(pool + 20480);

    const int b = blockIdx.y;
    const int tile = blockIdx.x;
    const int t = threadIdx.x;
    const int w = t >> 6;
    const int lane = t & 63;
    const int g = lane >> 4;
    const int c = lane & 15;
    const int jh = w >> 2;   // j-half
    const int sq = w & 3;    // q-subtile

    for (int i = t; i < 64 * DD; i += 512) wo_lds[i] = wo[i];
    if (t < 64) bo_lds[t] = bo[t];

    {   // V LDS rows 24..31 (both halves), once: row 24 = 1.0 (denominator), 25..31 = 0
        const int half = t >> 8, rr = 24 + ((t >> 5) & 7), col4 = (t & 31) * 4;
        const unsigned short val = (rr == 24) ? (unsigned short)0x3F80 : (unsigned short)0;
        unsigned short* dst = vpool + half * 4352 + rr * 136 + col4;
        dst[0] = val; dst[1] = val; dst[2] = val; dst[3] = val;
    }

    const int qrow_g = tile * 64 + sq * 16 + c;
    const short8 qf = *(const short8*)(qr + ((size_t)(b * NPIX + qrow_g)) * DP + g * 8);

    const unsigned short* kb = kr + (size_t)b * NPIX * DP;
    const unsigned short* vb = vdn + (size_t)b * DD * NPIX;

    // K staging (r3 verbatim): thread -> row t>>1, 32B half t&1, bit-permuted dest row
    const int krow = t >> 1, khw = t & 1;
    const int kh = krow >> 7, kjn = krow & 127;
    const int klow = kjn & 63;
    const int kR = (kjn & 64) + ((klow >> 5) & 1) * 32 + ((klow >> 2) & 1) * 16
                 + ((klow >> 4) & 1) * 8 + ((klow >> 3) & 1) * 4 + (klow & 3);
    unsigned short* kdst = kpool + kh * 5120 + kR * 40 + khw * 16;
    const unsigned short* ksrc0 = kb + ((size_t)(kh * 4608 + kjn)) * DP + khw * 16;
    // V staging rows 0..23 only (384 active threads)
    const int vu = t >> 3, vpt = t & 7;
    const int vhh = (vu >= 24) ? 1 : 0;
    const int vd = vu - 24 * vhh;
    unsigned short* vdst = vpool + vhh * 4352 + vd * 136 + vpt * 16;
    const unsigned short* vsrc0 = vb + (size_t)vd * NPIX + vhh * 4608 + vpt * 16;

    const unsigned short* kT = kpool + jh * 5120;   // this wave's K buffer [128][40]
    const unsigned short* vT = vpool + jh * 4352;   // this wave's V buffer [32][136]

    f32x4 acc0 = {0.f, 0.f, 0.f, 0.f};   // O^T[d=4g+r][q=c]   (unnormalized)
    f32x4 acc1 = {0.f, 0.f, 0.f, 0.f};   // O^T[16+4g+r][q=c]; row 24 = denominator
    float m = -INFINITY;                  // per-q running max (log2 domain)
    const f32x4 zf = {0.f, 0.f, 0.f, 0.f};

    for (int it = 0; it < 36; ++it) {
        const int jt = it * 128;
        __syncthreads();
        {   // stage both halves' K/V tiles
            const u32x4* sk = (const u32x4*)(ksrc0 + (size_t)jt * DP);
            u32x4 a0 = sk[0], a1 = sk[1];
            *(u32x4*)kdst = a0; *(u32x4*)(kdst + 8) = a1;
            if (t < 384) {
                const u32x4* sv = (const u32x4*)(vsrc0 + jt);
                u32x4 b0 = sv[0], b1 = sv[1];
                *(u32x4*)vdst = b0; *(u32x4*)(vdst + 8) = b1;
            }
        }
        __syncthreads();

#pragma unroll
        for (int u = 0; u < 2; ++u) {   // two 64-j groups per 128-tile
            const int jb = u * 64;
            const short8 kf0 = *(const short8*)(kT + (jb +  0 + c) * 40 + g * 8);
            const short8 kf1 = *(const short8*)(kT + (jb + 16 + c) * 40 + g * 8);
            const short8 kf2 = *(const short8*)(kT + (jb + 32 + c) * 40 + g * 8);
            const short8 kf3 = *(const short8*)(kT + (jb + 48 + c) * 40 + g * 8);
            __builtin_amdgcn_s_setprio(1);
            f32x4 s0 = __builtin_amdgcn_mfma_f32_16x16x32_bf16(kf0, qf, zf, 0, 0, 0);
            f32x4 s1 = __builtin_amdgcn_mfma_f32_16x16x32_bf16(kf1, qf, zf, 0, 0, 0);
            f32x4 s2 = __builtin_amdgcn_mfma_f32_16x16x32_bf16(kf2, qf, zf, 0, 0, 0);
            f32x4 s3 = __builtin_amdgcn_mfma_f32_16x16x32_bf16(kf3, qf, zf, 0, 0, 0);
            __builtin_amdgcn_s_setprio(0);

            float a0 = fmaxf(fmaxf(s0[0], s0[1]), fmaxf(s0[2], s0[3]));
            float a1 = fmaxf(fmaxf(s1[0], s1[1]), fmaxf(s1[2], s1[3]));
            float a2 = fmaxf(fmaxf(s2[0], s2[1]), fmaxf(s2[2], s2[3]));
            float a3 = fmaxf(fmaxf(s3[0], s3[1]), fmaxf(s3[2], s3[3]));
            float pmax = fmaxf(fmaxf(a0, a1), fmaxf(a2, a3));
            pmax = fmaxf(pmax, __shfl_xor(pmax, 16));
            pmax = fmaxf(pmax, __shfl_xor(pmax, 32));

            if (__any(pmax > m + 8.0f)) {   // defer-max: exact, rarely taken after tile 0
                const float mn = fmaxf(m, pmax);
                const float al = __builtin_amdgcn_exp2f(m - mn);   // 0 on first tile
                m = mn;
#pragma unroll
                for (int r = 0; r < 4; ++r) { acc0[r] *= al; acc1[r] *= al; }
            }

            float p0[4], p1[4], p2[4], p3[4];
#pragma unroll
            for (int r = 0; r < 4; ++r) {
                p0[r] = __builtin_amdgcn_exp2f(s0[r] - m);
                p1[r] = __builtin_amdgcn_exp2f(s1[r] - m);
                p2[r] = __builtin_amdgcn_exp2f(s2[r] - m);
                p3[r] = __builtin_amdgcn_exp2f(s3[r] - m);
            }

            // lane-local B-fragments of P^T (thanks to the K-row permutation, r3-verified)
            union { short8 s8; unsigned int u32[4]; } b2a, b2b;
            b2a.u32[0] = pkbf(p0[0], p0[1]); b2a.u32[1] = pkbf(p0[2], p0[3]);
            b2a.u32[2] = pkbf(p1[0], p1[1]); b2a.u32[3] = pkbf(p1[2], p1[3]);
            b2b.u32[0] = pkbf(p2[0], p2[1]); b2b.u32[1] = pkbf(p2[2], p2[3]);
            b2b.u32[2] = pkbf(p3[0], p3[1]); b2b.u32[3] = pkbf(p3[2], p3[3]);

            const short8 vl0 = *(const short8*)(vT + (c)      * 136 + jb +      g * 8);
            const short8 vh0 = *(const short8*)(vT + (16 + c) * 136 + jb +      g * 8);
            const short8 vl1 = *(const short8*)(vT + (c)      * 136 + jb + 32 + g * 8);
            const short8 vh1 = *(const short8*)(vT + (16 + c) * 136 + jb + 32 + g * 8);
            __builtin_amdgcn_s_setprio(1);
            acc0 = __builtin_amdgcn_mfma_f32_16x16x32_bf16(vl0, b2a.s8, acc0, 0, 0, 0);
            acc1 = __builtin_amdgcn_mfma_f32_16x16x32_bf16(vh0, b2a.s8, acc1, 0, 0, 0);
            acc0 = __builtin_amdgcn_mfma_f32_16x16x32_bf16(vl1, b2b.s8, acc0, 0, 0, 0);
            acc1 = __builtin_amdgcn_mfma_f32_16x16x32_bf16(vh1, b2b.s8, acc1, 0, 0, 0);
            __builtin_amdgcn_s_setprio(0);
        }
    }
    __syncthreads();   // staging buffers dead; reuse pool as merge scratch

    float* om  = (float*)pool;            // [8][16][36]  (18432 B); col 24 = denom
    float* mlb = (float*)(pool + 18432);  // [8][16] running max
    *(f32x4*)(om + (w * 16 + c) * 36 + 4 * g) = acc0;
    *(f32x4*)(om + (w * 16 + c) * 36 + 16 + 4 * g) = acc1;
    if (g == 0) mlb[w * 16 + c] = m;
    __syncthreads();

    // merge the two j-half partials for q-subtile sq, then 1x1 out-projection.
    const float mA = mlb[sq * 16 + c], mB = mlb[(sq + 4) * 16 + c];
    const float M  = fmaxf(mA, mB);
    const float wA = __builtin_amdgcn_exp2f(mA - M);
    const float wB = __builtin_amdgcn_exp2f(mB - M);
    const float lA = om[(sq * 16 + c) * 36 + 24];
    const float lB = om[((sq + 4) * 16 + c) * 36 + 24];
    const float inv = 1.0f / (lA * wA + lB * wB);
    float orw[DD];
#pragma unroll
    for (int d = 0; d < DD; ++d)
        orw[d] = (om[(sq * 16 + c) * 36 + d] * wA + om[((sq + 4) * 16 + c) * 36 + d] * wB) * inv;

#pragma unroll
    for (int tt = 0; tt < 8; ++tt) {
        const int o = g + 4 * (jh * 8 + tt);
        float a = bo_lds[o];
#pragma unroll
        for (int d = 0; d < DD; ++d) a = fmaf(wo_lds[o * DD + d], orw[d], a);
        out[((size_t)(b * 64 + o)) * NPIX + qrow_g] = a;
    }
}

extern "C" void kernel_launch(void* const* d_in, const int* in_sizes, int n_in,
                              void* d_out, int out_size, void* d_ws, size_t ws_size,
                              hipStream_t stream) {
    const float* x  = (const float*)d_in[0];
    const float* wq = (const float*)d_in[1];
    const float* bq = (const float*)d_in[2];
    const float* wk = (const float*)d_in[3];
    const float* bk = (const float*)d_in[4];
    const float* wv = (const float*)d_in[5];
    const float* bv = (const float*)d_in[6];
    const float* wo = (const float*)d_in[7];
    const float* bo = (const float*)d_in[8];
    float* out = (float*)d_out;

    unsigned short* qr  = (unsigned short*)d_ws;                 // 4*9216*32 bf16
    unsigned short* kr  = qr + (size_t)4 * NPIX * DP;
    unsigned short* vdn = kr + (size_t)4 * NPIX * DP;            // 4*24*9216 bf16

    hipLaunchKernelGGL(qkv_proj_kernel, dim3(4 * NPIX / 256, 3), dim3(256), 0, stream,
                       x, wq, bq, wk, bk, wv, bv, qr, kr, vdn);
    hipLaunchKernelGGL(attn_kernel, dim3(NPIX / 64, 4), dim3(512), 0, stream,
                       qr, kr, vdn, wo, bo, out);
}

// Round 6
// 130.216 us; speedup vs baseline: 4.0089x; 1.0043x over previous
//
#include <hip/hip_runtime.h>
#include <stdint.h>

#define NPIX 9216   // 96*96
#define CIN 64
#define DD 24
#define DP 32       // padded head dim (24 -> 32, zeros)
#define JQ 2304     // j per quarter
#define NIT 36      // 2304 / 64

typedef __attribute__((ext_vector_type(8))) short short8;   // 8 bf16
typedef __attribute__((ext_vector_type(4))) float f32x4;
typedef __attribute__((ext_vector_type(4))) unsigned int u32x4;

__device__ __forceinline__ unsigned short f2bf(float f) {
    unsigned int u = __builtin_bit_cast(unsigned int, f);
    u += 0x7fffu + ((u >> 16) & 1u);
    return (unsigned short)(u >> 16);
}
// packed f32x2 -> bf16x2 in one VALU op (T12 recipe; dst.lo = first operand)
__device__ __forceinline__ unsigned int pkbf(float lo, float hi) {
    unsigned int r;
    asm("v_cvt_pk_bf16_f32 %0, %1, %2" : "=v"(r) : "v"(lo), "v"(hi));
    return r;
}

// ---------------- Kernel 1: QKV projection (one proj per thread) ----------------
// grid (144, 3): blockIdx.y = projection (0=Q,1=K,2=V).
// qr, kr: [B, N, 32] bf16 (q pre-scaled by log2e/sqrt(24)); vdn: [B, 24, N] bf16.
__global__ __launch_bounds__(256) void qkv_proj_kernel(
    const float* __restrict__ x,
    const float* __restrict__ wq, const float* __restrict__ bq,
    const float* __restrict__ wk, const float* __restrict__ bk,
    const float* __restrict__ wv, const float* __restrict__ bv,
    unsigned short* __restrict__ qr, unsigned short* __restrict__ kr,
    unsigned short* __restrict__ vdn)
{
    const int p = blockIdx.y;
    const int tid = blockIdx.x * 256 + threadIdx.x;
    const int b = tid / NPIX;
    const int n = tid - b * NPIX;
    const float* xb = x + (size_t)b * CIN * NPIX + n;
    float xv[CIN];
#pragma unroll
    for (int c = 0; c < CIN; ++c) xv[c] = xb[(size_t)c * NPIX];

    const float* wm = (p == 0) ? wq : (p == 1) ? wk : wv;
    const float* bm = (p == 0) ? bq : (p == 1) ? bk : bv;

    float acc[DD];
#pragma unroll
    for (int d = 0; d < DD; ++d) acc[d] = bm[d];
#pragma unroll 4
    for (int c = 0; c < CIN; ++c) {
        const float xc = xv[c];
#pragma unroll
        for (int d = 0; d < DD; ++d) acc[d] = fmaf(wm[d * CIN + c], xc, acc[d]);
    }

    if (p == 2) {           // V: d-major rows 0..23 (ones/zero rows 24..31 built in attn LDS)
        const size_t vbase = (size_t)b * DD * NPIX + n;
#pragma unroll
        for (int d = 0; d < DD; ++d) vdn[vbase + (size_t)d * NPIX] = f2bf(acc[d]);
    } else {
        alignas(16) unsigned short row[DP];
        const float sc = (p == 0) ? (float)(0.20412414523193154 * 1.4426950408889634) : 1.0f;
#pragma unroll
        for (int d = 0; d < DD; ++d) row[d] = f2bf(acc[d] * sc);
#pragma unroll
        for (int d = DD; d < DP; ++d) row[d] = 0;
        unsigned short* dst = ((p == 0) ? qr : kr) + (size_t)(b * NPIX + n) * DP;
        const u32x4* r4 = (const u32x4*)row;
#pragma unroll
        for (int i = 0; i < 4; ++i) ((u32x4*)dst)[i] = r4[i];
    }
}

// ---------------- Kernel 2: flash attention (16x16 MFMA, 4-way j-split) ----------------
// grid (288, 4), 512 threads = 8 waves: wave w -> q-subtile sq = w>>2 (16 rows of the
// block's 32), j-quarter p = w&3 (2304 j). T14 prefetch: next tile global->regs during
// compute. K rows staged bit-permuted (r3-verified) -> exp'd P packs pairwise into PV
// B-frags, zero cross-lane movement. V LDS row 24 = 1.0 -> PV row 24 = softmax denom.
__global__ __launch_bounds__(512) void attn_kernel(
    const unsigned short* __restrict__ qr,
    const unsigned short* __restrict__ kr,
    const unsigned short* __restrict__ vdn,
    const float* __restrict__ wo, const float* __restrict__ bo,
    float* __restrict__ out)
{
    __shared__ __align__(16) unsigned char pool[20480 + 18432]; // K [4][64][40]u16, V [4][32][72]u16
    __shared__ float wo_lds[64 * DD];
    __shared__ float bo_lds[64];
    unsigned short* kpool = (unsigned short*)pool;              // quarter p at p*2560
    unsigned short* vpool = (unsigned short*)(pool + 20480);    // quarter p at p*2304

    const int b = blockIdx.y, tile = blockIdx.x;
    const int t = threadIdx.x;
    const int w = t >> 6, lane = t & 63;
    const int g = lane >> 4, c = lane & 15;
    const int sq = w >> 2;   // q-subtile (0/1)
    const int p  = w & 3;    // j-quarter

    for (int i = t; i < 64 * DD; i += 512) wo_lds[i] = wo[i];
    if (t < 64) bo_lds[t] = bo[t];

    // V rows 24..31 per quarter, once: row 24 = 1.0 (denominator trick), 25..31 = 0
    for (int i = t; i < 4 * 8 * 72; i += 512) {
        const int q_ = i / 576, rem = i - q_ * 576;
        const int r_ = rem / 72, col = rem - r_ * 72;
        vpool[q_ * 2304 + (24 + r_) * 72 + col] = (r_ == 0) ? (unsigned short)0x3F80 : 0;
    }

    const int qrow_g = tile * 32 + sq * 16 + c;
    const short8 qf = *(const short8*)(qr + ((size_t)(b * NPIX + qrow_g)) * DP + g * 8);

    const unsigned short* kb = kr + (size_t)b * NPIX * DP;
    const unsigned short* vb = vdn + (size_t)b * DD * NPIX;

    // K staging: thread t -> quarter kq = t>>7, row kjn = (t>>1)&63, 32B half khw = t&1;
    // dest row bit-permuted (r3-verified low-6 permutation)
    const int khw = t & 1, kq = t >> 7, kjn = (t >> 1) & 63;
    const int kR = ((kjn >> 5) & 1) * 32 + ((kjn >> 2) & 1) * 16
                 + ((kjn >> 4) & 1) * 8 + ((kjn >> 3) & 1) * 4 + (kjn & 3);
    unsigned short* kdst = kpool + kq * 2560 + kR * 40 + khw * 16;
    const unsigned short* ksrc0 = kb + ((size_t)(kq * JQ + kjn)) * DP + khw * 16;

    // V staging rows 0..23 (384 threads): vq = t/96, vd = (t%96)>>2, 32B piece vpt = t&3
    const int vq = t / 96, vrem = t - vq * 96, vd = vrem >> 2, vpt = t & 3;
    unsigned short* vdst = vpool + vq * 2304 + vd * 72 + vpt * 16;
    const unsigned short* vsrc0 = vb + (size_t)vd * NPIX + vq * JQ + vpt * 16;

    const unsigned short* kT = kpool + p * 2560;   // this wave's K tile [64][40]
    const unsigned short* vT = vpool + p * 2304;   // this wave's V tile [32][72]

    f32x4 acc0 = {0.f, 0.f, 0.f, 0.f};   // O^T[d=4g+r][q=c] (unnormalized)
    f32x4 acc1 = {0.f, 0.f, 0.f, 0.f};   // O^T[16+4g+r][q=c]; row 24 = denominator
    float m = -INFINITY;
    const f32x4 zf = {0.f, 0.f, 0.f, 0.f};

    // prefetch tile 0 into regs
    u32x4 pk0, pk1, pv0, pv1;
    {
        const u32x4* sk = (const u32x4*)ksrc0;
        pk0 = sk[0]; pk1 = sk[1];
        if (t < 384) { const u32x4* sv = (const u32x4*)vsrc0; pv0 = sv[0]; pv1 = sv[1]; }
    }

    for (int it = 0; it < NIT; ++it) {
        __syncthreads();                       // previous tile's readers done
        *(u32x4*)kdst = pk0; *(u32x4*)(kdst + 8) = pk1;
        if (t < 384) { *(u32x4*)vdst = pv0; *(u32x4*)(vdst + 8) = pv1; }
        __syncthreads();

        if (it + 1 < NIT) {                    // T14: issue next tile's loads now,
            const int jn = (it + 1) * 64;      // latency hides under compute below
            const u32x4* sk = (const u32x4*)(ksrc0 + (size_t)jn * DP);
            pk0 = sk[0]; pk1 = sk[1];
            if (t < 384) { const u32x4* sv = (const u32x4*)(vsrc0 + jn); pv0 = sv[0]; pv1 = sv[1]; }
        }

        // ---- compute one 64-j tile (r3/r5-verified group structure) ----
        const short8 kf0 = *(const short8*)(kT + ( 0 + c) * 40 + g * 8);
        const short8 kf1 = *(const short8*)(kT + (16 + c) * 40 + g * 8);
        const short8 kf2 = *(const short8*)(kT + (32 + c) * 40 + g * 8);
        const short8 kf3 = *(const short8*)(kT + (48 + c) * 40 + g * 8);
        __builtin_amdgcn_s_setprio(1);
        f32x4 s0 = __builtin_amdgcn_mfma_f32_16x16x32_bf16(kf0, qf, zf, 0, 0, 0);
        f32x4 s1 = __builtin_amdgcn_mfma_f32_16x16x32_bf16(kf1, qf, zf, 0, 0, 0);
        f32x4 s2 = __builtin_amdgcn_mfma_f32_16x16x32_bf16(kf2, qf, zf, 0, 0, 0);
        f32x4 s3 = __builtin_amdgcn_mfma_f32_16x16x32_bf16(kf3, qf, zf, 0, 0, 0);
        __builtin_amdgcn_s_setprio(0);

        float a0 = fmaxf(fmaxf(s0[0], s0[1]), fmaxf(s0[2], s0[3]));
        float a1 = fmaxf(fmaxf(s1[0], s1[1]), fmaxf(s1[2], s1[3]));
        float a2 = fmaxf(fmaxf(s2[0], s2[1]), fmaxf(s2[2], s2[3]));
        float a3 = fmaxf(fmaxf(s3[0], s3[1]), fmaxf(s3[2], s3[3]));
        float pmax = fmaxf(fmaxf(a0, a1), fmaxf(a2, a3));
        pmax = fmaxf(pmax, __shfl_xor(pmax, 16));
        pmax = fmaxf(pmax, __shfl_xor(pmax, 32));

        if (__any(pmax > m + 8.0f)) {          // defer-max: exact, rarely taken after tile 0
            const float mn = fmaxf(m, pmax);
            const float al = __builtin_amdgcn_exp2f(m - mn);   // 0 on first tile
            m = mn;
#pragma unroll
            for (int r = 0; r < 4; ++r) { acc0[r] *= al; acc1[r] *= al; }
        }

        float p0[4], p1[4], p2[4], p3[4];
#pragma unroll
        for (int r = 0; r < 4; ++r) {
            p0[r] = __builtin_amdgcn_exp2f(s0[r] - m);
            p1[r] = __builtin_amdgcn_exp2f(s1[r] - m);
            p2[r] = __builtin_amdgcn_exp2f(s2[r] - m);
            p3[r] = __builtin_amdgcn_exp2f(s3[r] - m);
        }

        union { short8 s8; unsigned int u32[4]; } b2a, b2b;
        b2a.u32[0] = pkbf(p0[0], p0[1]); b2a.u32[1] = pkbf(p0[2], p0[3]);
        b2a.u32[2] = pkbf(p1[0], p1[1]); b2a.u32[3] = pkbf(p1[2], p1[3]);
        b2b.u32[0] = pkbf(p2[0], p2[1]); b2b.u32[1] = pkbf(p2[2], p2[3]);
        b2b.u32[2] = pkbf(p3[0], p3[1]); b2b.u32[3] = pkbf(p3[2], p3[3]);

        const short8 vl0 = *(const short8*)(vT + (c)      * 72 +      g * 8);
        const short8 vh0 = *(const short8*)(vT + (16 + c) * 72 +      g * 8);
        const short8 vl1 = *(const short8*)(vT + (c)      * 72 + 32 + g * 8);
        const short8 vh1 = *(const short8*)(vT + (16 + c) * 72 + 32 + g * 8);
        __builtin_amdgcn_s_setprio(1);
        acc0 = __builtin_amdgcn_mfma_f32_16x16x32_bf16(vl0, b2a.s8, acc0, 0, 0, 0);
        acc1 = __builtin_amdgcn_mfma_f32_16x16x32_bf16(vh0, b2a.s8, acc1, 0, 0, 0);
        acc0 = __builtin_amdgcn_mfma_f32_16x16x32_bf16(vl1, b2b.s8, acc0, 0, 0, 0);
        acc1 = __builtin_amdgcn_mfma_f32_16x16x32_bf16(vh1, b2b.s8, acc1, 0, 0, 0);
        __builtin_amdgcn_s_setprio(0);
    }
    __syncthreads();   // staging buffers dead; reuse pool as merge scratch

    float* om  = (float*)pool;            // [8 waves][16 q][36] f32; col 24 = denom
    float* mlb = (float*)(pool + 18432);  // [8][16] running max
    *(f32x4*)(om + (w * 16 + c) * 36 + 4 * g) = acc0;
    *(f32x4*)(om + (w * 16 + c) * 36 + 16 + 4 * g) = acc1;
    if (g == 0) mlb[w * 16 + c] = m;
    __syncthreads();

    // 4-way merge + 1x1 out-projection. thread t: q = t&31, channel group og = t>>5.
    const int ql = t & 31, og = t >> 5;
    const int wbase = (ql >> 4) * 4, qc = ql & 15;
    const float m0 = mlb[(wbase + 0) * 16 + qc];
    const float m1 = mlb[(wbase + 1) * 16 + qc];
    const float m2 = mlb[(wbase + 2) * 16 + qc];
    const float m3 = mlb[(wbase + 3) * 16 + qc];
    const float M  = fmaxf(fmaxf(m0, m1), fmaxf(m2, m3));
    const float w0 = __builtin_amdgcn_exp2f(m0 - M);
    const float w1 = __builtin_amdgcn_exp2f(m1 - M);
    const float w2 = __builtin_amdgcn_exp2f(m2 - M);
    const float w3 = __builtin_amdgcn_exp2f(m3 - M);
    const float* o0 = om + ((wbase + 0) * 16 + qc) * 36;
    const float* o1 = om + ((wbase + 1) * 16 + qc) * 36;
    const float* o2 = om + ((wbase + 2) * 16 + qc) * 36;
    const float* o3 = om + ((wbase + 3) * 16 + qc) * 36;
    const float inv = 1.0f / (w0 * o0[24] + w1 * o1[24] + w2 * o2[24] + w3 * o3[24]);
    float od[DD];
#pragma unroll
    for (int d = 0; d < DD; ++d)
        od[d] = (w0 * o0[d] + w1 * o1[d] + w2 * o2[d] + w3 * o3[d]) * inv;

    const int n_g = tile * 32 + ql;
#pragma unroll
    for (int oo = 0; oo < 4; ++oo) {
        const int o = og * 4 + oo;
        float a = bo_lds[o];
#pragma unroll
        for (int d = 0; d < DD; ++d) a = fmaf(wo_lds[o * DD + d], od[d], a);
        out[((size_t)(b * 64 + o)) * NPIX + n_g] = a;
    }
}

extern "C" void kernel_launch(void* const* d_in, const int* in_sizes, int n_in,
                              void* d_out, int out_size, void* d_ws, size_t ws_size,
                              hipStream_t stream) {
    const float* x  = (const float*)d_in[0];
    const float* wq = (const float*)d_in[1];
    const float* bq = (const float*)d_in[2];
    const float* wk = (const float*)d_in[3];
    const float* bk = (const float*)d_in[4];
    const float* wv = (const float*)d_in[5];
    const float* bv = (const float*)d_in[6];
    const float* wo = (const float*)d_in[7];
    const float* bo = (const float*)d_in[8];
    float* out = (float*)d_out;

    unsigned short* qr  = (unsigned short*)d_ws;                 // 4*9216*32 bf16
    unsigned short* kr  = qr + (size_t)4 * NPIX * DP;
    unsigned short* vdn = kr + (size_t)4 * NPIX * DP;            // 4*24*9216 bf16

    hipLaunchKernelGGL(qkv_proj_kernel, dim3(4 * NPIX / 256, 3), dim3(256), 0, stream,
                       x, wq, bq, wk, bk, wv, bv, qr, kr, vdn);
    hipLaunchKernelGGL(attn_kernel, dim3(NPIX / 32, 4), dim3(512), 0, stream,
                       qr, kr, vdn, wo, bo, out);
}